// Round 11
// baseline (276.601 us; speedup 1.0000x reference)
//
#include <hip/hip_runtime.h>
#include <hip/hip_fp16.h>

// ---------------------------------------------------------------------------
// GCN: 2x GraphConv (norm='both') + FC.  fp32 math, fp16 intermediates.
// R2..R8: 5943 -> 325 us (CSR gather, fold FC, MFMA GEMMs, fp16, no atomics).
// R9-R11: reservation partition, lane tuning. 323 us.
// R12/R13: XCD-affinity sliced gather. REGRESSED: per-XCD L2 replication of
//      shared tables is structural (gather FETCH 178 MB == 8 x 22 MB
//      compulsory; rate ~3.1-3.6 TB/s == miss-concurrency cap).
// R14: pad G rows to 128B + merged fine pass. 314.7 us.
// R15: W-frag preconversion; GEMMs LDS-free. 297.9 us.
// R16: 128-node buckets (fine 196->782 blocks). 290.0 us.
// R17: fused gemm40 into gather epilogue (h1 never hits HBM). 279.1 us.
// R18: (a) gather pre-splits bf16 into LDS (KEPT); (b) gemm128 64-row probe
//      REGRESSED (W-amortization > occupancy).
// R19: best-of-each recombination. 277.5 us.
// R20: CHUNK 8192 REGRESSED (313) but EXPOSED scatter: VALUBusy 0.9%,
//      occupancy 7.8% -> partition is LATENCY-bound.
// R21: 1024-thread scatter: only -2.4 us (LDS-atomic serialization traded
//      against latency hiding). 275.1 us. Per-kernel shaving exhausted.
// R22: STRUCTURAL: co-launch scatter (latency-bound) and gemm128 (compute-
//      bound) as ONE fat kernel with disjoint block ranges -- they co-reside
//      per CU and fill each other's bubbles. Enabled by deferring norm_out
//      out of gemm128 (Y = X@W1 unscaled; gather becomes weighted:
//      acc += norm_out[s] * Y[s], norm table L2-hot). One launch fewer.
// ---------------------------------------------------------------------------

#define CHUNK    4096   // edges per scatter block (391 blocks)
#define NBK      800    // bin array size (>= nbuck=782)
#define SLAB     3072   // per-bucket slab capacity (mean 2046 + ~22 sigma)

typedef __attribute__((ext_vector_type(8))) short bf16x8;
typedef __attribute__((ext_vector_type(4))) float f32x4;

struct __align__(8)  half4 { __half x, y, z, w; };
struct __align__(16) half8 { __half h[8]; };

__device__ __forceinline__ unsigned short f2bf(float f) {
    union { float f; unsigned u; } v; v.f = f;
    unsigned r = v.u + 0x7FFFu + ((v.u >> 16) & 1u);   // RNE
    return (unsigned short)(r >> 16);
}
__device__ __forceinline__ float bf2f(unsigned short h) {
    union { unsigned u; float f; } v; v.u = ((unsigned)h) << 16;
    return v.f;
}

// ---------------------------------------------------------------------------
// setup: cursors, W1 -> frag-ordered bf16-split (Wh1/Wl1, 16384 each),
// W2p = W2@Wfc folded+converted (Wh2/Wl2, 48x128 = 6144 each, cols>=40 zero),
// b2p = b2@Wfc + bfc.
// ---------------------------------------------------------------------------
__global__ void setup_kernel(const float* __restrict__ W1, const float* __restrict__ W2,
                             const float* __restrict__ Wfc,
                             const float* __restrict__ b2, const float* __restrict__ bfc,
                             unsigned short* __restrict__ Wh1, unsigned short* __restrict__ Wl1,
                             unsigned short* __restrict__ Wh2, unsigned short* __restrict__ Wl2,
                             float* __restrict__ b2p,
                             int* __restrict__ cur_d, int* __restrict__ cur_s, int nbuck) {
    int idx = blockIdx.x * blockDim.x + threadIdx.x;
    if (idx < nbuck) { cur_d[idx] = idx * SLAB; cur_s[idx] = idx * SLAB; }

    if (idx < 16384) {
        // W1[k][nn] -> frag pos for gemm128
        int k = idx >> 7, nn = idx & 127;
        float v = W1[idx];
        int q = k >> 5, j = k & 7, lb = ((k >> 3) & 3) * 16;
        int tcol = nn >> 4;
        int l = lb + (nn & 15);
        int pos = ((tcol * 4 + q) * 64 + l) * 8 + j;
        unsigned short h = f2bf(v);
        Wh1[pos] = h;
        Wl1[pos] = f2bf(v - bf2f(h));
    } else if (idx < 16384 + 6144) {
        // W2p[k][nn] = dot(W2 row k, Wfc col nn) -> frag pos for fused gemm40
        int i2 = idx - 16384;
        int k = i2 / 48, nn = i2 - k * 48;
        float v = 0.f;
        if (nn < 40) {
            const float* w2row = W2 + k * 128;
            #pragma unroll 8
            for (int jj = 0; jj < 128; ++jj) v += w2row[jj] * Wfc[jj * 40 + nn];
        }
        int t = nn >> 4, q = k >> 5, j = k & 7;
        int l = ((k >> 3) & 3) * 16 + (nn & 15);
        int pos = ((t * 4 + q) * 64 + l) * 8 + j;
        unsigned short h = f2bf(v);
        Wh2[pos] = h;
        Wl2[pos] = f2bf(v - bf2f(h));
    } else if (idx < 16384 + 6144 + 40) {
        int c = idx - (16384 + 6144);
        float a = bfc[c];
        #pragma unroll 8
        for (int j = 0; j < 128; ++j) a += b2[j] * Wfc[j * 40 + c];
        b2p[c] = a;
    }
}

// ---------------------------------------------------------------------------
// FAT co-launch kernel.
// Blocks [0, nsc): edge partition (R19 256-thread scatter, CHUNK 4096).
//   Latency-bound (miss-chains, LDS atomics), VALU ~1%.
// Blocks [nsc, ...): Y[nrows x 128] = X @ W1 (UNSCALED) via MFMA bf16-split.
//   Compute-bound, needs ~12 waves/CU.
// The two block types co-reside per CU and fill each other's pipeline
// bubbles; buffers are disjoint (ppack/es_loc vs Y).
// ---------------------------------------------------------------------------
__global__ __launch_bounds__(256, 3) void fat_kernel(
        const int* __restrict__ src, const int* __restrict__ dst,
        int* __restrict__ cur_d, int* __restrict__ cur_s,
        unsigned int* __restrict__ ppack, unsigned char* __restrict__ es_loc,
        int E, int nsc,
        const float* __restrict__ X,
        const unsigned short* __restrict__ Wh, const unsigned short* __restrict__ Wl,
        __half* __restrict__ Y, int nrows) {
    __shared__ int hd[NBK], hs[NBK], bd[NBK], bs[NBK];
    const int tid = threadIdx.x;

    if (blockIdx.x < nsc) {
        // ---------------- scatter path ----------------
        for (int i = tid; i < NBK; i += 256) { hd[i] = 0; hs[i] = 0; }
        __syncthreads();
        const int base = blockIdx.x * CHUNK;
        const int end  = min(base + CHUNK, E);
        for (int e = base + tid; e < end; e += 256) {
            atomicAdd(&hd[((unsigned)dst[e]) >> 7], 1);
            atomicAdd(&hs[((unsigned)src[e]) >> 7], 1);
        }
        __syncthreads();
        for (int i = tid; i < NBK; i += 256) {
            int cd = hd[i];
            bd[i] = cd ? atomicAdd(&cur_d[i], cd) : 0;
            hd[i] = 0;
            int cs = hs[i];
            bs[i] = cs ? atomicAdd(&cur_s[i], cs) : 0;
            hs[i] = 0;
        }
        __syncthreads();
        for (int e = base + tid; e < end; e += 256) {
            int d = dst[e], s = src[e];
            unsigned bin_d = ((unsigned)d) >> 7;
            int pos = bd[bin_d] + atomicAdd(&hd[bin_d], 1);
            ppack[pos] = (((unsigned)d & 127u) << 17) | (unsigned)s;
            unsigned bin_s = ((unsigned)s) >> 7;
            int ps = bs[bin_s] + atomicAdd(&hs[bin_s], 1);
            es_loc[ps] = (unsigned char)(s & 127);
        }
        return;
    }

    // ---------------- gemm path (unscaled) ----------------
    const int blk  = blockIdx.x - nsc;
    const int lane = tid & 63;
    const int w    = tid >> 6;
    const int m    = lane & 15;
    const int quad = lane >> 4;
    const int rowBase = blk * 128 + w * 32;

    bf16x8 Ah[2][4], Al[2][4];
    #pragma unroll
    for (int rt = 0; rt < 2; ++rt) {
        int r = rowBase + rt * 16 + m;
        const float* xr = X + (size_t)(r < nrows ? r : 0) * 128;
        const float z = (r < nrows) ? 1.f : 0.f;
        #pragma unroll
        for (int q = 0; q < 4; ++q) {
            int k0 = q * 32 + quad * 8;
            float4 a = *(const float4*)(xr + k0);
            float4 bv = *(const float4*)(xr + k0 + 4);
            float v[8] = {a.x * z, a.y * z, a.z * z, a.w * z,
                          bv.x * z, bv.y * z, bv.z * z, bv.w * z};
            bf16x8 hi, lo;
            #pragma unroll
            for (int j = 0; j < 8; ++j) {
                unsigned short h = f2bf(v[j]);
                hi[j] = (short)h;
                lo[j] = (short)f2bf(v[j] - bf2f(h));
            }
            Ah[rt][q] = hi; Al[rt][q] = lo;
        }
    }

    f32x4 acc[2][8];
    #pragma unroll
    for (int rt = 0; rt < 2; ++rt)
        #pragma unroll
        for (int t = 0; t < 8; ++t)
            acc[rt][t] = (f32x4){0.f, 0.f, 0.f, 0.f};

    #pragma unroll
    for (int t = 0; t < 8; ++t) {
        #pragma unroll
        for (int q = 0; q < 4; ++q) {
            const int off = ((t * 4 + q) * 64 + lane) * 8;
            bf16x8 Bh = *(const bf16x8*)(Wh + off);
            bf16x8 Bl = *(const bf16x8*)(Wl + off);
            #pragma unroll
            for (int rt = 0; rt < 2; ++rt) {
                acc[rt][t] = __builtin_amdgcn_mfma_f32_16x16x32_bf16(Ah[rt][q], Bh, acc[rt][t], 0, 0, 0);
                acc[rt][t] = __builtin_amdgcn_mfma_f32_16x16x32_bf16(Ah[rt][q], Bl, acc[rt][t], 0, 0, 0);
                acc[rt][t] = __builtin_amdgcn_mfma_f32_16x16x32_bf16(Al[rt][q], Bh, acc[rt][t], 0, 0, 0);
            }
        }
    }

    #pragma unroll
    for (int rt = 0; rt < 2; ++rt) {
        int r0 = rowBase + rt * 16 + quad * 4;
        #pragma unroll
        for (int reg = 0; reg < 4; ++reg) {
            int r = r0 + reg;
            if (r >= nrows) continue;
            __half* yr = Y + (size_t)r * 128 + m;
            #pragma unroll
            for (int t = 0; t < 8; ++t)
                yr[t * 16] = __float2half(acc[rt][t][reg]);
        }
    }
}

// ------------- per-bucket fine pass: dst (CSR) + src (norm_out) merged ------
// one block per 128-node bucket (782 blocks, ~2046 entries each)
__global__ __launch_bounds__(256) void fine_kernel(
        const unsigned int* __restrict__ ppack, const int* __restrict__ cur_d,
        const unsigned char* __restrict__ es_loc, const int* __restrict__ cur_s,
        int* __restrict__ deg_in, float* __restrict__ norm_in,
        int* __restrict__ row_ptr, int* __restrict__ csr_src,
        float* __restrict__ norm_out, int N_) {
    __shared__ int h[128];
    __shared__ int psum[128];
    const int tid = threadIdx.x;
    const int b = blockIdx.x;
    const int start = b * SLAB;
    const int node  = (b << 7) + tid;

    // ---- dst: histogram -> prefix -> CSR scatter ----
    const int end_d = cur_d[b];
    if (tid < 128) h[tid] = 0;
    __syncthreads();
    for (int i = start + tid; i < end_d; i += 256)
        atomicAdd(&h[ppack[i] >> 17], 1);
    __syncthreads();

    int a = 0;
    if (tid < 128) { a = h[tid]; psum[tid] = a; }
    __syncthreads();
    for (int off = 1; off < 128; off <<= 1) {
        int t = 0;
        if (tid < 128 && tid >= off) t = psum[tid - off];
        __syncthreads();
        if (tid < 128) psum[tid] += t;
        __syncthreads();
    }

    if (tid < 128) {
        int base0 = psum[tid] - a + start;   // slab-local CSR position
        if (node < N_) {
            deg_in[node]  = a;
            row_ptr[node] = base0;
            norm_in[node] = rsqrtf((float)(a < 1 ? 1 : a));
        }
        h[tid] = base0;
    }
    __syncthreads();

    for (int i = start + tid; i < end_d; i += 256) {
        unsigned int pk = ppack[i];
        int pos = atomicAdd(&h[pk >> 17], 1);
        csr_src[pos] = (int)(pk & 0x1FFFFu);
    }
    __syncthreads();

    // ---- src: histogram -> norm_out ----
    const int end_s = cur_s[b];
    if (tid < 128) h[tid] = 0;
    __syncthreads();
    for (int i = start + tid; i < end_s; i += 256)
        atomicAdd(&h[(int)es_loc[i]], 1);
    __syncthreads();

    if (tid < 128 && node < N_) {
        int d = h[tid];
        norm_out[node] = rsqrtf((float)(d < 1 ? 1 : d));
    }
}

// ---------------------------------------------------------------------------
// FUSED WEIGHTED gather + layer-1 GEMM.
// Phase 1 (all 256 threads): h1[node] = relu((sum_s no[s]*Y[s]) * ni + b1)
//   (Y is UNSCALED X@W1; norm_out applied per-edge, table L2-hot), then
//   pre-scaled by norm_out[node] and SPLIT to bf16 hi/lo in LDS.
// Phase 2 (waves 0-2): pure ds_read_b128 A-frags + 12 MFMA -> G[16 x 40].
// h1 never touches global memory.
// ---------------------------------------------------------------------------
__global__ __launch_bounds__(256, 4) void gather_kernel(
        const __half* __restrict__ H, const int* __restrict__ row_ptr,
        const int* __restrict__ deg, const int* __restrict__ csr_src,
        const float* __restrict__ norm_in, const float* __restrict__ b,
        const float* __restrict__ norm_out,
        const unsigned short* __restrict__ Wh2, const unsigned short* __restrict__ Wl2,
        __half* __restrict__ G, int n) {
    __shared__ unsigned short h1h[16][136];   // bf16 hi, stride 136 (2-way alias max)
    __shared__ unsigned short h1l[16][136];   // bf16 lo
    const int tid   = threadIdx.x;
    const int node0 = blockIdx.x * 16;
    const int g     = tid >> 4;              // node-in-block 0..15
    const int node  = node0 + g;
    const int c     = (tid & 15) * 8;        // column group
    const bool active = node < n;

    int start = 0, cnt = 0;
    if (active) { start = row_ptr[node]; cnt = deg[node]; }
    float acc[8] = {0.f, 0.f, 0.f, 0.f, 0.f, 0.f, 0.f, 0.f};

    int j = 0;
    for (; j + 4 <= cnt; j += 4) {
        int s0 = csr_src[start + j];
        int s1 = csr_src[start + j + 1];
        int s2 = csr_src[start + j + 2];
        int s3 = csr_src[start + j + 3];
        float n0 = norm_out[s0], n1 = norm_out[s1];
        float n2 = norm_out[s2], n3 = norm_out[s3];
        half8 v0 = *(const half8*)(H + (long long)s0 * 128 + c);
        half8 v1 = *(const half8*)(H + (long long)s1 * 128 + c);
        half8 v2 = *(const half8*)(H + (long long)s2 * 128 + c);
        half8 v3 = *(const half8*)(H + (long long)s3 * 128 + c);
        #pragma unroll
        for (int k = 0; k < 8; ++k) {
            float t0 = fmaf(n0, __half2float(v0.h[k]), fmaf(n1, __half2float(v1.h[k]), acc[k]));
            acc[k] = fmaf(n2, __half2float(v2.h[k]), fmaf(n3, __half2float(v3.h[k]), t0));
        }
    }
    for (; j < cnt; ++j) {
        int s0 = csr_src[start + j];
        float n0 = norm_out[s0];
        half8 v0 = *(const half8*)(H + (long long)s0 * 128 + c);
        #pragma unroll
        for (int k = 0; k < 8; ++k) acc[k] = fmaf(n0, __half2float(v0.h[k]), acc[k]);
    }

    float ni = active ? norm_in[node]  : 0.f;
    float no = active ? norm_out[node] : 0.f;   // layer-1 row scale, pre-applied
    float4 b0  = *(const float4*)(b + c);
    float4 b1v = *(const float4*)(b + c + 4);
    float bb[8] = {b0.x, b0.y, b0.z, b0.w, b1v.x, b1v.y, b1v.z, b1v.w};
    bf16x8 hi, lo;
    #pragma unroll
    for (int k = 0; k < 8; ++k) {
        float hv = fmaxf(acc[k] * ni + bb[k], 0.f) * no;
        unsigned short h = f2bf(hv);
        hi[k] = (short)h;
        lo[k] = (short)f2bf(hv - bf2f(h));
    }
    *(bf16x8*)&h1h[g][c] = hi;
    *(bf16x8*)&h1l[g][c] = lo;
    __syncthreads();

    // phase 2: waves 0..2 each compute one 16-col tile of G (pure LDS+MFMA)
    const int w = tid >> 6;
    if (w < 3) {
        const int lane = tid & 63;
        const int m    = lane & 15;
        const int quad = lane >> 4;

        f32x4 a3 = (f32x4){0.f, 0.f, 0.f, 0.f};
        const int t = w;
        #pragma unroll
        for (int q = 0; q < 4; ++q) {
            const int k0 = q * 32 + quad * 8;
            bf16x8 Ah = *(const bf16x8*)&h1h[m][k0];
            bf16x8 Al = *(const bf16x8*)&h1l[m][k0];
            const int off = ((t * 4 + q) * 64 + lane) * 8;
            bf16x8 Bh = *(const bf16x8*)(Wh2 + off);
            bf16x8 Bl = *(const bf16x8*)(Wl2 + off);
            a3 = __builtin_amdgcn_mfma_f32_16x16x32_bf16(Ah, Bh, a3, 0, 0, 0);
            a3 = __builtin_amdgcn_mfma_f32_16x16x32_bf16(Ah, Bl, a3, 0, 0, 0);
            a3 = __builtin_amdgcn_mfma_f32_16x16x32_bf16(Al, Bh, a3, 0, 0, 0);
        }

        const int col = t * 16 + m;
        if (col < 40) {
            const int r0 = node0 + quad * 4;
            #pragma unroll
            for (int reg = 0; reg < 4; ++reg) {
                int r = r0 + reg;
                if (r < n) G[(size_t)r * 64 + col] = __float2half(a3[reg]);
            }
        }
    }
}

// 40-dim gather (fp16 in, PADDED stride 64; fp32 out): out = (sum G[src])*ni + b2p
// 5 lanes per node, one half8 (16 B) each.
__global__ __launch_bounds__(256) void gather40_kernel(
        const __half* __restrict__ G, const int* __restrict__ row_ptr,
        const int* __restrict__ deg, const int* __restrict__ csr_src,
        const float* __restrict__ norm_in, const float* __restrict__ b2p,
        float* __restrict__ out, int n) {
    const int t = blockIdx.x * 256 + threadIdx.x;
    if (t >= n * 5) return;
    const int node = t / 5;
    const int c    = (t - node * 5) * 8;

    const int start = row_ptr[node];
    const int cnt   = deg[node];
    float acc[8] = {0.f, 0.f, 0.f, 0.f, 0.f, 0.f, 0.f, 0.f};

    int j = 0;
    for (; j + 4 <= cnt; j += 4) {
        int s0 = csr_src[start + j];
        int s1 = csr_src[start + j + 1];
        int s2 = csr_src[start + j + 2];
        int s3 = csr_src[start + j + 3];
        half8 v0 = *(const half8*)(G + (long long)s0 * 64 + c);
        half8 v1 = *(const half8*)(G + (long long)s1 * 64 + c);
        half8 v2 = *(const half8*)(G + (long long)s2 * 64 + c);
        half8 v3 = *(const half8*)(G + (long long)s3 * 64 + c);
        #pragma unroll
        for (int k = 0; k < 8; ++k)
            acc[k] += (__half2float(v0.h[k]) + __half2float(v1.h[k]))
                    + (__half2float(v2.h[k]) + __half2float(v3.h[k]));
    }
    for (; j < cnt; ++j) {
        int s0 = csr_src[start + j];
        half8 v0 = *(const half8*)(G + (long long)s0 * 64 + c);
        #pragma unroll
        for (int k = 0; k < 8; ++k) acc[k] += __half2float(v0.h[k]);
    }

    float ni = norm_in[node];
    float4 o0, o1;
    o0.x = acc[0] * ni + b2p[c + 0];
    o0.y = acc[1] * ni + b2p[c + 1];
    o0.z = acc[2] * ni + b2p[c + 2];
    o0.w = acc[3] * ni + b2p[c + 3];
    o1.x = acc[4] * ni + b2p[c + 4];
    o1.y = acc[5] * ni + b2p[c + 5];
    o1.z = acc[6] * ni + b2p[c + 6];
    o1.w = acc[7] * ni + b2p[c + 7];
    float* op = out + (long long)node * 40 + c;
    *(float4*)(op)     = o0;
    *(float4*)(op + 4) = o1;
}

extern "C" void kernel_launch(void* const* d_in, const int* in_sizes, int n_in,
                              void* d_out, int out_size, void* d_ws, size_t ws_size,
                              hipStream_t stream) {
    const float* x   = (const float*)d_in[0];
    const int*   ei  = (const int*)  d_in[1];
    const float* W1  = (const float*)d_in[2];
    const float* b1  = (const float*)d_in[3];
    const float* W2  = (const float*)d_in[4];
    const float* b2  = (const float*)d_in[5];
    const float* Wfc = (const float*)d_in[6];
    const float* bfc = (const float*)d_in[7];
    float* out = (float*)d_out;

    const int N = in_sizes[0] / 128;
    const int E = in_sizes[1] / 2;
    const int* src = ei;
    const int* dst = ei + E;

    const int nbuck = (N + 127) >> 7;                  // 782
    const int nsc   = (E + CHUNK - 1) / CHUNK;         // 391 scatter blocks
    const int gemm_grid = (N + 127) / 128;             // 782 gemm blocks

    char* p = (char*)d_ws;
    float* norm_out = (float*)p; p += (size_t)N * 4;
    float* norm_in  = (float*)p; p += (size_t)N * 4;
    float* bufA     = (float*)p; p += (size_t)N * 128 * 4;   // h1pre fp16
    float* bufB     = (float*)p; p += (size_t)N * 128 * 4;   // slabs, then G fp16
    int*   deg_in   = (int*)p;   p += (size_t)N * 4;
    int*   row_ptr  = (int*)p;   p += (size_t)N * 4;
    int*   csr_src  = (int*)p;   p += (size_t)NBK * SLAB * 4;   // slab-indexed CSR
    int*   cur_d    = (int*)p;   p += (size_t)1024 * 4;
    int*   cur_s    = (int*)p;   p += (size_t)1024 * 4;
    float* b2p      = (float*)p; p += (size_t)64 * 4;
    unsigned short* Wh1 = (unsigned short*)p; p += (size_t)16384 * 2;
    unsigned short* Wl1 = (unsigned short*)p; p += (size_t)16384 * 2;
    unsigned short* Wh2 = (unsigned short*)p; p += (size_t)6144 * 2;
    unsigned short* Wl2 = (unsigned short*)p; p += (size_t)6144 * 2;

    // partition slabs alias bufB (consumed by fine_kernel before gather
    // writes G there)
    unsigned int*  ppack  = (unsigned int*)bufB;
    unsigned char* es_loc = (unsigned char*)(ppack + (size_t)NBK * SLAB);

    __half* h1pre = (__half*)bufA;   // N x 128 fp16 (UNSCALED X@W1)
    __half* G     = (__half*)bufB;   // N x 64 fp16 PADDED (fused-gather output)

    const int T = 256;

    // setup: cursors + W1/W2p frag conversion + b2p
    setup_kernel<<<(16384 + 6144 + 40 + T - 1) / T, T, 0, stream>>>(
        W1, W2, Wfc, b2, bfc, Wh1, Wl1, Wh2, Wl2, b2p, cur_d, cur_s, nbuck);
    // FAT co-launch: scatter (blocks 0..nsc-1) || unscaled gemm128 (rest)
    fat_kernel<<<nsc + gemm_grid, T, 0, stream>>>(
        src, dst, cur_d, cur_s, ppack, es_loc, E, nsc,
        x, Wh1, Wl1, h1pre, N);
    fine_kernel<<<nbuck, T, 0, stream>>>(ppack, cur_d, es_loc, cur_s,
                                         deg_in, norm_in, row_ptr, csr_src,
                                         norm_out, N);
    // fused weighted gather: sum no[s]*Y[s] -> relu -> (h1*no)@W2p -> G
    const int gather_grid = (N + 15) / 16;
    gather_kernel<<<gather_grid, T, 0, stream>>>(h1pre, row_ptr, deg_in, csr_src,
                                                 norm_in, b1, norm_out,
                                                 Wh2, Wl2, G, N);
    // final gather + bias: out = gather(G) * ni + b2p
    gather40_kernel<<<((size_t)N * 5 + T - 1) / T, T, 0, stream>>>(
        G, row_ptr, deg_in, csr_src, norm_in, b2p, out, N);
}

// Round 12
// 271.002 us; speedup vs baseline: 1.0207x; 1.0207x over previous
//
#include <hip/hip_runtime.h>
#include <hip/hip_fp16.h>

// ---------------------------------------------------------------------------
// GCN: 2x GraphConv (norm='both') + FC.  fp32 math, fp16 intermediates.
// R2..R8: 5943 -> 325 us (CSR gather, fold FC, MFMA GEMMs, fp16, no atomics).
// R9-R11: reservation partition, lane tuning. 323 us.
// R12/R13: XCD-affinity sliced gather. REGRESSED: per-XCD L2 replication of
//      shared tables is structural (gather FETCH 178 MB == 8 x 22 MB
//      compulsory; rate ~3.1-3.6 TB/s == miss-concurrency cap).
// R14: pad G rows to 128B + merged fine pass. 314.7 us.
// R15: W-frag preconversion; GEMMs LDS-free. 297.9 us.
// R16: 128-node buckets (fine 196->782 blocks). 290.0 us.
// R17: fused gemm40 into gather epilogue (h1 never hits HBM). 279.1 us.
// R18: gather pre-splits bf16 into LDS (KEPT); gemm128 64-row probe REGRESSED.
// R19: best-of-each recombination. 277.5 us.
// R20: CHUNK 8192 REGRESSED (313) but EXPOSED scatter as latency-bound
//      (VALUBusy 0.9%, occ 7.8%).
// R21: 1024-thread scatter: -2.4 us. 275.1 us.
// R22: scatter||gemm co-launch NEUTRAL (276.6): fat = serial sum, not max --
//      gemm starved scatter's latency-hiding waves. Weighted-gather +
//      unscaled-gemm algebra validated.
// R23: co-launch pairing fixed: fine||gemm (even/odd interleave, 782+782
//      blocks). fine streams L2-resident slabs (latency-robust), gemm is
//      MFMA-bound -- complementary. Scatter back to standalone 1024-thread.
//      One launch fewer than R21.
// ---------------------------------------------------------------------------

#define CHUNK    4096   // edges per scatter block (391 blocks)
#define NBK      800    // bin array size (>= nbuck=782)
#define SLAB     3072   // per-bucket slab capacity (mean 2046 + ~22 sigma)

typedef __attribute__((ext_vector_type(8))) short bf16x8;
typedef __attribute__((ext_vector_type(4))) float f32x4;

struct __align__(8)  half4 { __half x, y, z, w; };
struct __align__(16) half8 { __half h[8]; };

__device__ __forceinline__ unsigned short f2bf(float f) {
    union { float f; unsigned u; } v; v.f = f;
    unsigned r = v.u + 0x7FFFu + ((v.u >> 16) & 1u);   // RNE
    return (unsigned short)(r >> 16);
}
__device__ __forceinline__ float bf2f(unsigned short h) {
    union { unsigned u; float f; } v; v.u = ((unsigned)h) << 16;
    return v.f;
}

// ---------------------------------------------------------------------------
// setup: cursors, W1 -> frag-ordered bf16-split (Wh1/Wl1, 16384 each),
// W2p = W2@Wfc folded+converted (Wh2/Wl2, 48x128 = 6144 each, cols>=40 zero),
// b2p = b2@Wfc + bfc.
// ---------------------------------------------------------------------------
__global__ void setup_kernel(const float* __restrict__ W1, const float* __restrict__ W2,
                             const float* __restrict__ Wfc,
                             const float* __restrict__ b2, const float* __restrict__ bfc,
                             unsigned short* __restrict__ Wh1, unsigned short* __restrict__ Wl1,
                             unsigned short* __restrict__ Wh2, unsigned short* __restrict__ Wl2,
                             float* __restrict__ b2p,
                             int* __restrict__ cur_d, int* __restrict__ cur_s, int nbuck) {
    int idx = blockIdx.x * blockDim.x + threadIdx.x;
    if (idx < nbuck) { cur_d[idx] = idx * SLAB; cur_s[idx] = idx * SLAB; }

    if (idx < 16384) {
        // W1[k][nn] -> frag pos for gemm128
        int k = idx >> 7, nn = idx & 127;
        float v = W1[idx];
        int q = k >> 5, j = k & 7, lb = ((k >> 3) & 3) * 16;
        int tcol = nn >> 4;
        int l = lb + (nn & 15);
        int pos = ((tcol * 4 + q) * 64 + l) * 8 + j;
        unsigned short h = f2bf(v);
        Wh1[pos] = h;
        Wl1[pos] = f2bf(v - bf2f(h));
    } else if (idx < 16384 + 6144) {
        // W2p[k][nn] = dot(W2 row k, Wfc col nn) -> frag pos for fused gemm40
        int i2 = idx - 16384;
        int k = i2 / 48, nn = i2 - k * 48;
        float v = 0.f;
        if (nn < 40) {
            const float* w2row = W2 + k * 128;
            #pragma unroll 8
            for (int jj = 0; jj < 128; ++jj) v += w2row[jj] * Wfc[jj * 40 + nn];
        }
        int t = nn >> 4, q = k >> 5, j = k & 7;
        int l = ((k >> 3) & 3) * 16 + (nn & 15);
        int pos = ((t * 4 + q) * 64 + l) * 8 + j;
        unsigned short h = f2bf(v);
        Wh2[pos] = h;
        Wl2[pos] = f2bf(v - bf2f(h));
    } else if (idx < 16384 + 6144 + 40) {
        int c = idx - (16384 + 6144);
        float a = bfc[c];
        #pragma unroll 8
        for (int j = 0; j < 128; ++j) a += b2[j] * Wfc[j * 40 + c];
        b2p[c] = a;
    }
}

// ------------- single-pass partition with per-bucket slab reservation -------
// buckets = node>>7 (128 nodes each, 782 buckets), 782 LDS bins.
// 1024 threads/block (16 waves): best measured (R21).
__global__ __launch_bounds__(1024) void scatter_res_kernel(
        const int* __restrict__ src, const int* __restrict__ dst,
        int* __restrict__ cur_d, int* __restrict__ cur_s,
        unsigned int* __restrict__ ppack, unsigned char* __restrict__ es_loc,
        int E) {
    __shared__ int hd[NBK], hs[NBK], bd[NBK], bs[NBK];
    const int tid = threadIdx.x;
    for (int i = tid; i < NBK; i += 1024) { hd[i] = 0; hs[i] = 0; }
    __syncthreads();
    const int base = blockIdx.x * CHUNK;
    const int end  = min(base + CHUNK, E);
    for (int e = base + tid; e < end; e += 1024) {
        atomicAdd(&hd[((unsigned)dst[e]) >> 7], 1);
        atomicAdd(&hs[((unsigned)src[e]) >> 7], 1);
    }
    __syncthreads();
    for (int i = tid; i < NBK; i += 1024) {
        int cd = hd[i];
        bd[i] = cd ? atomicAdd(&cur_d[i], cd) : 0;
        hd[i] = 0;
        int cs = hs[i];
        bs[i] = cs ? atomicAdd(&cur_s[i], cs) : 0;
        hs[i] = 0;
    }
    __syncthreads();
    for (int e = base + tid; e < end; e += 1024) {
        int d = dst[e], s = src[e];
        unsigned bin_d = ((unsigned)d) >> 7;
        int pos = bd[bin_d] + atomicAdd(&hd[bin_d], 1);
        ppack[pos] = (((unsigned)d & 127u) << 17) | (unsigned)s;
        unsigned bin_s = ((unsigned)s) >> 7;
        int ps = bs[bin_s] + atomicAdd(&hs[bin_s], 1);
        es_loc[ps] = (unsigned char)(s & 127);
    }
}

// ---------------------------------------------------------------------------
// CO-LAUNCH: fine (even blocks) || unscaled gemm128 (odd blocks).
// nbuck == gemm_grid == ceil(N/128) -> perfect interleave; every CU hosts a
// mix of {slab-streaming fine} and {MFMA-bound gemm} blocks.
// ---------------------------------------------------------------------------
__global__ __launch_bounds__(256, 3) void fine_gemm_kernel(
        const unsigned int* __restrict__ ppack, const int* __restrict__ cur_d,
        const unsigned char* __restrict__ es_loc, const int* __restrict__ cur_s,
        int* __restrict__ deg_in, float* __restrict__ norm_in,
        int* __restrict__ row_ptr, int* __restrict__ csr_src,
        float* __restrict__ norm_out, int N_,
        const float* __restrict__ X,
        const unsigned short* __restrict__ Wh, const unsigned short* __restrict__ Wl,
        __half* __restrict__ Y) {
    const int tid = threadIdx.x;

    if ((blockIdx.x & 1) == 0) {
        // ---------------- fine path (bucket b) ----------------
        __shared__ int h[128];
        __shared__ int psum[128];
        const int b = blockIdx.x >> 1;
        const int start = b * SLAB;
        const int node  = (b << 7) + tid;

        // dst: histogram -> prefix -> CSR scatter
        const int end_d = cur_d[b];
        if (tid < 128) h[tid] = 0;
        __syncthreads();
        for (int i = start + tid; i < end_d; i += 256)
            atomicAdd(&h[ppack[i] >> 17], 1);
        __syncthreads();

        int a = 0;
        if (tid < 128) { a = h[tid]; psum[tid] = a; }
        __syncthreads();
        for (int off = 1; off < 128; off <<= 1) {
            int t = 0;
            if (tid < 128 && tid >= off) t = psum[tid - off];
            __syncthreads();
            if (tid < 128) psum[tid] += t;
            __syncthreads();
        }

        if (tid < 128) {
            int base0 = psum[tid] - a + start;   // slab-local CSR position
            if (node < N_) {
                deg_in[node]  = a;
                row_ptr[node] = base0;
                norm_in[node] = rsqrtf((float)(a < 1 ? 1 : a));
            }
            h[tid] = base0;
        }
        __syncthreads();

        for (int i = start + tid; i < end_d; i += 256) {
            unsigned int pk = ppack[i];
            int pos = atomicAdd(&h[pk >> 17], 1);
            csr_src[pos] = (int)(pk & 0x1FFFFu);
        }
        __syncthreads();

        // src: histogram -> norm_out
        const int end_s = cur_s[b];
        if (tid < 128) h[tid] = 0;
        __syncthreads();
        for (int i = start + tid; i < end_s; i += 256)
            atomicAdd(&h[(int)es_loc[i]], 1);
        __syncthreads();

        if (tid < 128 && node < N_) {
            int d = h[tid];
            norm_out[node] = rsqrtf((float)(d < 1 ? 1 : d));
        }
        return;
    }

    // ---------------- gemm path (unscaled Y = X @ W1) ----------------
    const int blk  = blockIdx.x >> 1;
    const int lane = tid & 63;
    const int w    = tid >> 6;
    const int m    = lane & 15;
    const int quad = lane >> 4;
    const int rowBase = blk * 128 + w * 32;
    const int nrows = N_;

    bf16x8 Ah[2][4], Al[2][4];
    #pragma unroll
    for (int rt = 0; rt < 2; ++rt) {
        int r = rowBase + rt * 16 + m;
        const float* xr = X + (size_t)(r < nrows ? r : 0) * 128;
        const float z = (r < nrows) ? 1.f : 0.f;
        #pragma unroll
        for (int q = 0; q < 4; ++q) {
            int k0 = q * 32 + quad * 8;
            float4 a = *(const float4*)(xr + k0);
            float4 bv = *(const float4*)(xr + k0 + 4);
            float v[8] = {a.x * z, a.y * z, a.z * z, a.w * z,
                          bv.x * z, bv.y * z, bv.z * z, bv.w * z};
            bf16x8 hi, lo;
            #pragma unroll
            for (int j = 0; j < 8; ++j) {
                unsigned short h = f2bf(v[j]);
                hi[j] = (short)h;
                lo[j] = (short)f2bf(v[j] - bf2f(h));
            }
            Ah[rt][q] = hi; Al[rt][q] = lo;
        }
    }

    f32x4 acc[2][8];
    #pragma unroll
    for (int rt = 0; rt < 2; ++rt)
        #pragma unroll
        for (int t = 0; t < 8; ++t)
            acc[rt][t] = (f32x4){0.f, 0.f, 0.f, 0.f};

    #pragma unroll
    for (int t = 0; t < 8; ++t) {
        #pragma unroll
        for (int q = 0; q < 4; ++q) {
            const int off = ((t * 4 + q) * 64 + lane) * 8;
            bf16x8 Bh = *(const bf16x8*)(Wh + off);
            bf16x8 Bl = *(const bf16x8*)(Wl + off);
            #pragma unroll
            for (int rt = 0; rt < 2; ++rt) {
                acc[rt][t] = __builtin_amdgcn_mfma_f32_16x16x32_bf16(Ah[rt][q], Bh, acc[rt][t], 0, 0, 0);
                acc[rt][t] = __builtin_amdgcn_mfma_f32_16x16x32_bf16(Ah[rt][q], Bl, acc[rt][t], 0, 0, 0);
                acc[rt][t] = __builtin_amdgcn_mfma_f32_16x16x32_bf16(Al[rt][q], Bh, acc[rt][t], 0, 0, 0);
            }
        }
    }

    #pragma unroll
    for (int rt = 0; rt < 2; ++rt) {
        int r0 = rowBase + rt * 16 + quad * 4;
        #pragma unroll
        for (int reg = 0; reg < 4; ++reg) {
            int r = r0 + reg;
            if (r >= nrows) continue;
            __half* yr = Y + (size_t)r * 128 + m;
            #pragma unroll
            for (int t = 0; t < 8; ++t)
                yr[t * 16] = __float2half(acc[rt][t][reg]);
        }
    }
}

// ---------------------------------------------------------------------------
// FUSED WEIGHTED gather + layer-1 GEMM.
// Phase 1 (all 256 threads): h1[node] = relu((sum_s no[s]*Y[s]) * ni + b1)
//   (Y is UNSCALED X@W1; norm_out applied per-edge, table L2-hot), then
//   pre-scaled by norm_out[node] and SPLIT to bf16 hi/lo in LDS.
// Phase 2 (waves 0-2): pure ds_read_b128 A-frags + 12 MFMA -> G[16 x 40].
// h1 never touches global memory.
// ---------------------------------------------------------------------------
__global__ __launch_bounds__(256, 4) void gather_kernel(
        const __half* __restrict__ H, const int* __restrict__ row_ptr,
        const int* __restrict__ deg, const int* __restrict__ csr_src,
        const float* __restrict__ norm_in, const float* __restrict__ b,
        const float* __restrict__ norm_out,
        const unsigned short* __restrict__ Wh2, const unsigned short* __restrict__ Wl2,
        __half* __restrict__ G, int n) {
    __shared__ unsigned short h1h[16][136];   // bf16 hi, stride 136 (2-way alias max)
    __shared__ unsigned short h1l[16][136];   // bf16 lo
    const int tid   = threadIdx.x;
    const int node0 = blockIdx.x * 16;
    const int g     = tid >> 4;              // node-in-block 0..15
    const int node  = node0 + g;
    const int c     = (tid & 15) * 8;        // column group
    const bool active = node < n;

    int start = 0, cnt = 0;
    if (active) { start = row_ptr[node]; cnt = deg[node]; }
    float acc[8] = {0.f, 0.f, 0.f, 0.f, 0.f, 0.f, 0.f, 0.f};

    int j = 0;
    for (; j + 4 <= cnt; j += 4) {
        int s0 = csr_src[start + j];
        int s1 = csr_src[start + j + 1];
        int s2 = csr_src[start + j + 2];
        int s3 = csr_src[start + j + 3];
        float n0 = norm_out[s0], n1 = norm_out[s1];
        float n2 = norm_out[s2], n3 = norm_out[s3];
        half8 v0 = *(const half8*)(H + (long long)s0 * 128 + c);
        half8 v1 = *(const half8*)(H + (long long)s1 * 128 + c);
        half8 v2 = *(const half8*)(H + (long long)s2 * 128 + c);
        half8 v3 = *(const half8*)(H + (long long)s3 * 128 + c);
        #pragma unroll
        for (int k = 0; k < 8; ++k) {
            float t0 = fmaf(n0, __half2float(v0.h[k]), fmaf(n1, __half2float(v1.h[k]), acc[k]));
            acc[k] = fmaf(n2, __half2float(v2.h[k]), fmaf(n3, __half2float(v3.h[k]), t0));
        }
    }
    for (; j < cnt; ++j) {
        int s0 = csr_src[start + j];
        float n0 = norm_out[s0];
        half8 v0 = *(const half8*)(H + (long long)s0 * 128 + c);
        #pragma unroll
        for (int k = 0; k < 8; ++k) acc[k] = fmaf(n0, __half2float(v0.h[k]), acc[k]);
    }

    float ni = active ? norm_in[node]  : 0.f;
    float no = active ? norm_out[node] : 0.f;   // layer-1 row scale, pre-applied
    float4 b0  = *(const float4*)(b + c);
    float4 b1v = *(const float4*)(b + c + 4);
    float bb[8] = {b0.x, b0.y, b0.z, b0.w, b1v.x, b1v.y, b1v.z, b1v.w};
    bf16x8 hi, lo;
    #pragma unroll
    for (int k = 0; k < 8; ++k) {
        float hv = fmaxf(acc[k] * ni + bb[k], 0.f) * no;
        unsigned short h = f2bf(hv);
        hi[k] = (short)h;
        lo[k] = (short)f2bf(hv - bf2f(h));
    }
    *(bf16x8*)&h1h[g][c] = hi;
    *(bf16x8*)&h1l[g][c] = lo;
    __syncthreads();

    // phase 2: waves 0..2 each compute one 16-col tile of G (pure LDS+MFMA)
    const int w = tid >> 6;
    if (w < 3) {
        const int lane = tid & 63;
        const int m    = lane & 15;
        const int quad = lane >> 4;

        f32x4 a3 = (f32x4){0.f, 0.f, 0.f, 0.f};
        const int t = w;
        #pragma unroll
        for (int q = 0; q < 4; ++q) {
            const int k0 = q * 32 + quad * 8;
            bf16x8 Ah = *(const bf16x8*)&h1h[m][k0];
            bf16x8 Al = *(const bf16x8*)&h1l[m][k0];
            const int off = ((t * 4 + q) * 64 + lane) * 8;
            bf16x8 Bh = *(const bf16x8*)(Wh2 + off);
            bf16x8 Bl = *(const bf16x8*)(Wl2 + off);
            a3 = __builtin_amdgcn_mfma_f32_16x16x32_bf16(Ah, Bh, a3, 0, 0, 0);
            a3 = __builtin_amdgcn_mfma_f32_16x16x32_bf16(Ah, Bl, a3, 0, 0, 0);
            a3 = __builtin_amdgcn_mfma_f32_16x16x32_bf16(Al, Bh, a3, 0, 0, 0);
        }

        const int col = t * 16 + m;
        if (col < 40) {
            const int r0 = node0 + quad * 4;
            #pragma unroll
            for (int reg = 0; reg < 4; ++reg) {
                int r = r0 + reg;
                if (r < n) G[(size_t)r * 64 + col] = __float2half(a3[reg]);
            }
        }
    }
}

// 40-dim gather (fp16 in, PADDED stride 64; fp32 out): out = (sum G[src])*ni + b2p
// 5 lanes per node, one half8 (16 B) each.
__global__ __launch_bounds__(256) void gather40_kernel(
        const __half* __restrict__ G, const int* __restrict__ row_ptr,
        const int* __restrict__ deg, const int* __restrict__ csr_src,
        const float* __restrict__ norm_in, const float* __restrict__ b2p,
        float* __restrict__ out, int n) {
    const int t = blockIdx.x * 256 + threadIdx.x;
    if (t >= n * 5) return;
    const int node = t / 5;
    const int c    = (t - node * 5) * 8;

    const int start = row_ptr[node];
    const int cnt   = deg[node];
    float acc[8] = {0.f, 0.f, 0.f, 0.f, 0.f, 0.f, 0.f, 0.f};

    int j = 0;
    for (; j + 4 <= cnt; j += 4) {
        int s0 = csr_src[start + j];
        int s1 = csr_src[start + j + 1];
        int s2 = csr_src[start + j + 2];
        int s3 = csr_src[start + j + 3];
        half8 v0 = *(const half8*)(G + (long long)s0 * 64 + c);
        half8 v1 = *(const half8*)(G + (long long)s1 * 64 + c);
        half8 v2 = *(const half8*)(G + (long long)s2 * 64 + c);
        half8 v3 = *(const half8*)(G + (long long)s3 * 64 + c);
        #pragma unroll
        for (int k = 0; k < 8; ++k)
            acc[k] += (__half2float(v0.h[k]) + __half2float(v1.h[k]))
                    + (__half2float(v2.h[k]) + __half2float(v3.h[k]));
    }
    for (; j < cnt; ++j) {
        int s0 = csr_src[start + j];
        half8 v0 = *(const half8*)(G + (long long)s0 * 64 + c);
        #pragma unroll
        for (int k = 0; k < 8; ++k) acc[k] += __half2float(v0.h[k]);
    }

    float ni = norm_in[node];
    float4 o0, o1;
    o0.x = acc[0] * ni + b2p[c + 0];
    o0.y = acc[1] * ni + b2p[c + 1];
    o0.z = acc[2] * ni + b2p[c + 2];
    o0.w = acc[3] * ni + b2p[c + 3];
    o1.x = acc[4] * ni + b2p[c + 4];
    o1.y = acc[5] * ni + b2p[c + 5];
    o1.z = acc[6] * ni + b2p[c + 6];
    o1.w = acc[7] * ni + b2p[c + 7];
    float* op = out + (long long)node * 40 + c;
    *(float4*)(op)     = o0;
    *(float4*)(op + 4) = o1;
}

extern "C" void kernel_launch(void* const* d_in, const int* in_sizes, int n_in,
                              void* d_out, int out_size, void* d_ws, size_t ws_size,
                              hipStream_t stream) {
    const float* x   = (const float*)d_in[0];
    const int*   ei  = (const int*)  d_in[1];
    const float* W1  = (const float*)d_in[2];
    const float* b1  = (const float*)d_in[3];
    const float* W2  = (const float*)d_in[4];
    const float* b2  = (const float*)d_in[5];
    const float* Wfc = (const float*)d_in[6];
    const float* bfc = (const float*)d_in[7];
    float* out = (float*)d_out;

    const int N = in_sizes[0] / 128;
    const int E = in_sizes[1] / 2;
    const int* src = ei;
    const int* dst = ei + E;

    const int nbuck = (N + 127) >> 7;                  // 782 (== gemm grid)
    const int B1 = (E + CHUNK - 1) / CHUNK;            // 391 scatter blocks

    char* p = (char*)d_ws;
    float* norm_out = (float*)p; p += (size_t)N * 4;
    float* norm_in  = (float*)p; p += (size_t)N * 4;
    float* bufA     = (float*)p; p += (size_t)N * 128 * 4;   // h1pre fp16
    float* bufB     = (float*)p; p += (size_t)N * 128 * 4;   // slabs, then G fp16
    int*   deg_in   = (int*)p;   p += (size_t)N * 4;
    int*   row_ptr  = (int*)p;   p += (size_t)N * 4;
    int*   csr_src  = (int*)p;   p += (size_t)NBK * SLAB * 4;   // slab-indexed CSR
    int*   cur_d    = (int*)p;   p += (size_t)1024 * 4;
    int*   cur_s    = (int*)p;   p += (size_t)1024 * 4;
    float* b2p      = (float*)p; p += (size_t)64 * 4;
    unsigned short* Wh1 = (unsigned short*)p; p += (size_t)16384 * 2;
    unsigned short* Wl1 = (unsigned short*)p; p += (size_t)16384 * 2;
    unsigned short* Wh2 = (unsigned short*)p; p += (size_t)6144 * 2;
    unsigned short* Wl2 = (unsigned short*)p; p += (size_t)6144 * 2;

    // partition slabs alias bufB (consumed by fine before gather writes G)
    unsigned int*  ppack  = (unsigned int*)bufB;
    unsigned char* es_loc = (unsigned char*)(ppack + (size_t)NBK * SLAB);

    __half* h1pre = (__half*)bufA;   // N x 128 fp16 (UNSCALED X@W1)
    __half* G     = (__half*)bufB;   // N x 64 fp16 PADDED (fused-gather output)

    const int T = 256;

    // setup: cursors + W1/W2p frag conversion + b2p
    setup_kernel<<<(16384 + 6144 + 40 + T - 1) / T, T, 0, stream>>>(
        W1, W2, Wfc, b2, bfc, Wh1, Wl1, Wh2, Wl2, b2p, cur_d, cur_s, nbuck);
    // partition (1024-thread blocks, best measured)
    scatter_res_kernel<<<B1, 1024, 0, stream>>>(src, dst, cur_d, cur_s,
                                                ppack, es_loc, E);
    // CO-LAUNCH: fine (even) || unscaled gemm128 (odd), perfectly interleaved
    fine_gemm_kernel<<<2 * nbuck, T, 0, stream>>>(
        ppack, cur_d, es_loc, cur_s, deg_in, norm_in, row_ptr, csr_src,
        norm_out, N, x, Wh1, Wl1, h1pre);
    // fused weighted gather: sum no[s]*Y[s] -> relu -> (h1*no)@W2p -> G
    const int gather_grid = (N + 15) / 16;
    gather_kernel<<<gather_grid, T, 0, stream>>>(h1pre, row_ptr, deg_in, csr_src,
                                                 norm_in, b1, norm_out,
                                                 Wh2, Wl2, G, N);
    // final gather + bias: out = gather(G) * ni + b2p
    gather40_kernel<<<((size_t)N * 5 + T - 1) / T, T, 0, stream>>>(
        G, row_ptr, deg_in, csr_src, norm_in, b2p, out, N);
}